// Round 2
// baseline (206.995 us; speedup 1.0000x reference)
//
#include <hip/hip_runtime.h>

#define B_TOT 8192
#define L 200
#define D 64
#define DA 128
#define HSTRIDE 65  // padded LDS row stride (floats): bank = (l + j) % 32

// ---------- prep: M = W_q @ W_k^T (64x64), P = W_v @ W_o (64x64) ----------
__global__ __launch_bounds__(256) void prep_kernel(
    const float* __restrict__ Wq, const float* __restrict__ Wk,
    const float* __restrict__ Wv, const float* __restrict__ Wo,
    float* __restrict__ MP)
{
    int gid = blockIdx.x * 256 + threadIdx.x;
    if (gid < 4096) {
        int i = gid >> 6, j = gid & 63;
        float s = 0.f;
        #pragma unroll 8
        for (int a = 0; a < DA; ++a) s += Wq[i * DA + a] * Wk[j * DA + a];
        MP[gid] = s;                       // M[i][j] = sum_a Wq[i,a]*Wk[j,a]
    } else if (gid < 8192) {
        int g = gid - 4096;
        int i = g >> 6, j = g & 63;
        float s = 0.f;
        #pragma unroll 8
        for (int a = 0; a < DA; ++a) s += Wv[i * DA + a] * Wo[a * D + j];
        MP[gid] = s;                       // P[i][j] = sum_a Wv[i,a]*Wo[a,j]
    }
}

// ---------- main: one block per batch row ----------
__global__ __launch_bounds__(256) void attn_kernel(
    const float* __restrict__ target, const float* __restrict__ hist,
    const int* __restrict__ mask, const float* __restrict__ MP,
    float* __restrict__ out)
{
    __shared__ float h[L * HSTRIDE];   // 52000 B, padded rows
    __shared__ float ts[D];            // target row
    __shared__ float qs[D];            // q~ (later reused as c)
    __shared__ float a_s[L];           // relu'd masked scores
    __shared__ float cp[2][D];         // partial c

    const int b = blockIdx.x;
    const int tid = threadIdx.x;
    const float* __restrict__ hb = hist + (size_t)b * (L * D);

    if (tid < D) ts[tid] = target[b * D + tid];

    // stage history [200][64] -> LDS padded [200][65], coalesced float4 loads
    const float4* __restrict__ h4 = (const float4*)hb;
    for (int i = tid; i < (L * D) / 4; i += 256) {
        float4 v = h4[i];
        int row = i >> 4;            // 16 float4 per row
        int c4  = (i & 15) << 2;
        float* dst = &h[row * HSTRIDE + c4];
        dst[0] = v.x; dst[1] = v.y; dst[2] = v.z; dst[3] = v.w;
    }
    __syncthreads();

    // q~[j] = (1/sqrt(128)) * sum_i ts[i] * M[i][j]
    if (tid < D) {
        float s = 0.f;
        #pragma unroll 8
        for (int i = 0; i < D; ++i) s += ts[i] * MP[i * D + tid];
        qs[tid] = s * 0.088388347648318440550f;  // 1/sqrt(128)
    }
    __syncthreads();

    // scores: thread l computes dot(q~, h[l]), mask, relu
    if (tid < L) {
        const float* hr = &h[tid * HSTRIDE];
        float s = 0.f;
        #pragma unroll 8
        for (int j = 0; j < D; ++j) s += qs[j] * hr[j];
        int m = mask[b * L + tid];
        s = m ? s : 0.f;
        a_s[tid] = s > 0.f ? s : 0.f;
    }
    __syncthreads();

    // c[j] = sum_l a[l] * h[l][j], split over 2 row-groups of 100
    if (tid < 128) {
        int g = tid >> 6, j = tid & 63;
        int l0 = g * 100;
        float s = 0.f;
        for (int l = l0; l < l0 + 100; ++l) s += a_s[l] * h[l * HSTRIDE + j];
        cp[g][j] = s;
    }
    __syncthreads();

    if (tid < D) qs[tid] = cp[0][tid] + cp[1][tid];   // qs now holds c
    __syncthreads();

    // out[b][j] = sum_i c[i] * P[i][j] + target[b][j]
    if (tid < D) {
        float s = ts[tid];
        #pragma unroll 8
        for (int i = 0; i < D; ++i) s += qs[i] * MP[4096 + i * D + tid];
        out[b * D + tid] = s;
    }
}

extern "C" void kernel_launch(void* const* d_in, const int* in_sizes, int n_in,
                              void* d_out, int out_size, void* d_ws, size_t ws_size,
                              hipStream_t stream) {
    const float* target = (const float*)d_in[0];
    const float* hist   = (const float*)d_in[1];
    const int*   mask   = (const int*)d_in[2];
    const float* Wq     = (const float*)d_in[3];
    const float* Wk     = (const float*)d_in[4];
    const float* Wv     = (const float*)d_in[5];
    const float* Wo     = (const float*)d_in[6];
    float* outp = (float*)d_out;
    float* MP   = (float*)d_ws;   // 8192 floats: M (4096) then P (4096)

    prep_kernel<<<32, 256, 0, stream>>>(Wq, Wk, Wv, Wo, MP);
    attn_kernel<<<B_TOT, 256, 0, stream>>>(target, hist, mask, MP, outp);
}

// Round 3
// 97.592 us; speedup vs baseline: 2.1210x; 2.1210x over previous
//
#include <hip/hip_runtime.h>

#define B_TOT 8192
#define L 200
#define D 64
#define DA 128
#define INV_SCALE 0.088388347648318440550f  // 1/sqrt(128)

// ---------- prep1: M = W_q @ W_k^T (64x64), P = W_v @ W_o (64x64) ----------
__global__ __launch_bounds__(256) void prep_kernel(
    const float* __restrict__ Wq, const float* __restrict__ Wk,
    const float* __restrict__ Wv, const float* __restrict__ Wo,
    float* __restrict__ MP)
{
    int gid = blockIdx.x * 256 + threadIdx.x;
    if (gid < 4096) {
        int i = gid >> 6, j = gid & 63;
        float s = 0.f;
        #pragma unroll 8
        for (int a = 0; a < DA; ++a) s += Wq[i * DA + a] * Wk[j * DA + a];
        MP[gid] = s;                       // M[i][j]
    } else if (gid < 8192) {
        int g = gid - 4096;
        int i = g >> 6, j = g & 63;
        float s = 0.f;
        #pragma unroll 8
        for (int a = 0; a < DA; ++a) s += Wv[i * DA + a] * Wo[a * D + j];
        MP[gid] = s;                       // P[i][j]
    }
}

// ---------- prep2: Qt[b][j] = (1/sqrt(128)) * sum_i target[b][i] * M[i][j] ----------
__global__ __launch_bounds__(256) void qt_kernel(
    const float* __restrict__ target, const float* __restrict__ MP,
    float* __restrict__ Qt)
{
    __shared__ float ts[256];
    const int base = blockIdx.x * 256;          // 4 target rows per block
    ts[threadIdx.x] = target[base + threadIdx.x];
    __syncthreads();
    const int r = threadIdx.x >> 6, j = threadIdx.x & 63;
    float s = 0.f;
    #pragma unroll 8
    for (int i = 0; i < D; ++i) s += ts[r * D + i] * MP[i * D + j];
    Qt[base + threadIdx.x] = s * INV_SCALE;
}

// ---------- main: one wave per batch row, fully in-register ----------
// Chunk = 16 rows (4KB). Load f=0..3: float4 at flat offset f*256 + lane*4
//   -> row R + f*4 + (lane>>4), cols (lane&15)*4 .. +3. Perfectly contiguous
//   1KB per instruction. Dot-reduce across lanes sharing a row (xor 1,2,4,8);
//   the SAME registers then feed c += a*v. No LDS staging of history.
__global__ __launch_bounds__(256) void attn_kernel(
    const float* __restrict__ hist, const int* __restrict__ mask,
    const float* __restrict__ Qt, const float* __restrict__ target,
    const float* __restrict__ MP, float* __restrict__ out)
{
    __shared__ float c_lds[4][D];
    const int tid  = threadIdx.x;
    const int wave = tid >> 6, lane = tid & 63;
    const int b    = blockIdx.x * 4 + wave;
    const float* __restrict__ hb = hist + (size_t)b * (L * D);
    const int lr = lane >> 4;                   // row sub-index within f-group
    const float4 q = *(const float4*)(Qt + b * D + (lane & 15) * 4);
    const int mbase = b * L;

    float c0 = 0.f, c1 = 0.f, c2 = 0.f, c3 = 0.f;

    #define CHUNK_F(R, f)                                                   \
    {                                                                       \
        float4 v = *(const float4*)(hb + (R) * D + (f) * 256 + lane * 4);   \
        float s = v.x * q.x + v.y * q.y + v.z * q.z + v.w * q.w;            \
        s += __shfl_xor(s, 1);                                              \
        s += __shfl_xor(s, 2);                                              \
        s += __shfl_xor(s, 4);                                              \
        s += __shfl_xor(s, 8);                                              \
        int m = mask[mbase + (R) + (f) * 4 + lr];                           \
        float a = (m != 0 && s > 0.f) ? s : 0.f;                            \
        c0 += a * v.x; c1 += a * v.y; c2 += a * v.z; c3 += a * v.w;         \
    }

    for (int R = 0; R < 192; R += 16) {
        CHUNK_F(R, 0) CHUNK_F(R, 1) CHUNK_F(R, 2) CHUNK_F(R, 3)
    }
    // tail: rows 192..199 -> f = 0,1 only
    CHUNK_F(192, 0) CHUNK_F(192, 1)
    #undef CHUNK_F

    // reduce c across the 4 lanes sharing each column set (xor 16, 32)
    c0 += __shfl_xor(c0, 16); c0 += __shfl_xor(c0, 32);
    c1 += __shfl_xor(c1, 16); c1 += __shfl_xor(c1, 32);
    c2 += __shfl_xor(c2, 16); c2 += __shfl_xor(c2, 32);
    c3 += __shfl_xor(c3, 16); c3 += __shfl_xor(c3, 32);

    if (lane < 16) {
        float4* cc = (float4*)&c_lds[wave][lane * 4];
        *cc = make_float4(c0, c1, c2, c3);
    }
    __syncthreads();

    // epilogue: out[b][lane] = target[b][lane] + sum_i c[i] * P[i][lane]
    float s = target[b * D + lane];
    const float* __restrict__ P = MP + 4096;
    #pragma unroll 8
    for (int i = 0; i < D; ++i) s += c_lds[wave][i] * P[i * D + lane];
    out[b * D + lane] = s;
}

extern "C" void kernel_launch(void* const* d_in, const int* in_sizes, int n_in,
                              void* d_out, int out_size, void* d_ws, size_t ws_size,
                              hipStream_t stream) {
    const float* target = (const float*)d_in[0];
    const float* hist   = (const float*)d_in[1];
    const int*   mask   = (const int*)d_in[2];
    const float* Wq     = (const float*)d_in[3];
    const float* Wk     = (const float*)d_in[4];
    const float* Wv     = (const float*)d_in[5];
    const float* Wo     = (const float*)d_in[6];
    float* outp = (float*)d_out;

    float* MP = (float*)d_ws;                       // 8192 floats (32KB)
    float* Qt = (float*)((char*)d_ws + 32768);      // 8192*64 floats (2MB)

    prep_kernel<<<32, 256, 0, stream>>>(Wq, Wk, Wv, Wo, MP);
    qt_kernel<<<B_TOT / 4, 256, 0, stream>>>(target, MP, Qt);
    attn_kernel<<<B_TOT / 4, 256, 0, stream>>>(hist, mask, Qt, target, MP, outp);
}

// Round 4
// 79.550 us; speedup vs baseline: 2.6021x; 1.2268x over previous
//
#include <hip/hip_runtime.h>

#define B_TOT 8192
#define L 200
#define D 64
#define DA 128
#define INV_SCALE 0.088388347648318440550f  // 1/sqrt(128)

typedef float f32x4 __attribute__((ext_vector_type(4)));
typedef int   i32x4 __attribute__((ext_vector_type(4)));

// ---------- prep: M = W_q @ W_k^T (64x64), P = W_v @ W_o (64x64) ----------
__global__ __launch_bounds__(256) void prep_kernel(
    const float* __restrict__ Wq, const float* __restrict__ Wk,
    const float* __restrict__ Wv, const float* __restrict__ Wo,
    float* __restrict__ MP)
{
    int gid = blockIdx.x * 256 + threadIdx.x;
    if (gid < 4096) {
        int i = gid >> 6, j = gid & 63;
        float s = 0.f;
        #pragma unroll 8
        for (int a = 0; a < DA; ++a) s += Wq[i * DA + a] * Wk[j * DA + a];
        MP[gid] = s;                       // M[i][j]
    } else if (gid < 8192) {
        int g = gid - 4096;
        int i = g >> 6, j = g & 63;
        float s = 0.f;
        #pragma unroll 8
        for (int a = 0; a < DA; ++a) s += Wv[i * DA + a] * Wo[a * D + j];
        MP[gid] = s;                       // P[i][j]
    }
}

// ---------- main: one wave per batch row, fully in-register, fused q~ ----------
__global__ __launch_bounds__(256, 8) void attn_kernel(
    const float* __restrict__ hist, const int* __restrict__ mask,
    const float* __restrict__ target, const float* __restrict__ MP,
    float* __restrict__ out)
{
    __shared__ float smask[4][L];      // 3200 B: mask row per wave, as float
    __shared__ float c_lds[4][D];      // 1024 B

    const int tid  = threadIdx.x;
    const int wave = tid >> 6, lane = tid & 63;
    const int b    = blockIdx.x * 4 + wave;
    const float* __restrict__ hb = hist + (size_t)b * (L * D);
    const int lr = lane >> 4;

    // target element (reused as the residual in the epilogue)
    const float t = target[b * D + lane];

    // mask row -> LDS as floats (800 B per wave, one int4 load per lane<50)
    if (lane < 50) {
        i32x4 mv = *(const i32x4*)(mask + b * L + lane * 4);
        f32x4 mf = { (float)mv.x, (float)mv.y, (float)mv.z, (float)mv.w };
        *(f32x4*)&smask[wave][lane * 4] = mf;
    }

    // q~[lane] = INV_SCALE * sum_i t_i * M[i][lane]   (M is L1-resident, 16KB)
    float qacc = 0.f;
    #pragma unroll 8
    for (int i = 0; i < D; ++i)
        qacc += __shfl(t, i) * MP[i * D + lane];
    qacc *= INV_SCALE;

    // redistribute: lane needs q~[(lane&15)*4 + k], k=0..3
    const int qb = (lane & 15) * 4;
    f32x4 q;
    q.x = __shfl(qacc, qb + 0);
    q.y = __shfl(qacc, qb + 1);
    q.z = __shfl(qacc, qb + 2);
    q.w = __shfl(qacc, qb + 3);

    __syncthreads();   // smask visible

    // main loop: 16-row chunks (4KB), 4 nontemporal float4 loads in flight
    f32x4 c = { 0.f, 0.f, 0.f, 0.f };
    const float* hp = hb + lane * 4;

    #define PROC(v, R, f)                                                    \
    {                                                                        \
        float s = v.x * q.x + v.y * q.y + v.z * q.z + v.w * q.w;             \
        s += __shfl_xor(s, 1);                                               \
        s += __shfl_xor(s, 2);                                               \
        s += __shfl_xor(s, 4);                                               \
        s += __shfl_xor(s, 8);                                               \
        float mf = smask[wave][(R) + (f) * 4 + lr];                          \
        float a = fmaxf(s * mf, 0.f);                                        \
        c += v * a;                                                          \
    }

    for (int R = 0; R < 192; R += 16) {
        f32x4 v0 = __builtin_nontemporal_load((const f32x4*)(hp + R * 64));
        f32x4 v1 = __builtin_nontemporal_load((const f32x4*)(hp + R * 64 + 256));
        f32x4 v2 = __builtin_nontemporal_load((const f32x4*)(hp + R * 64 + 512));
        f32x4 v3 = __builtin_nontemporal_load((const f32x4*)(hp + R * 64 + 768));
        PROC(v0, R, 0) PROC(v1, R, 1) PROC(v2, R, 2) PROC(v3, R, 3)
    }
    {   // tail rows 192..199
        f32x4 v0 = __builtin_nontemporal_load((const f32x4*)(hp + 192 * 64));
        f32x4 v1 = __builtin_nontemporal_load((const f32x4*)(hp + 192 * 64 + 256));
        PROC(v0, 192, 0) PROC(v1, 192, 1)
    }
    #undef PROC

    // reduce c across the 4 lanes sharing each column group (xor 16, 32)
    c.x += __shfl_xor(c.x, 16); c.x += __shfl_xor(c.x, 32);
    c.y += __shfl_xor(c.y, 16); c.y += __shfl_xor(c.y, 32);
    c.z += __shfl_xor(c.z, 16); c.z += __shfl_xor(c.z, 32);
    c.w += __shfl_xor(c.w, 16); c.w += __shfl_xor(c.w, 32);

    if (lane < 16) *(f32x4*)&c_lds[wave][lane * 4] = c;
    __syncthreads();

    // epilogue: out[b][lane] = t + sum_i c[i] * P[i][lane]
    float s = t;
    const float* __restrict__ P = MP + 4096;
    #pragma unroll 8
    for (int i = 0; i < D; ++i) s += c_lds[wave][i] * P[i * D + lane];
    out[b * D + lane] = s;
}

extern "C" void kernel_launch(void* const* d_in, const int* in_sizes, int n_in,
                              void* d_out, int out_size, void* d_ws, size_t ws_size,
                              hipStream_t stream) {
    const float* target = (const float*)d_in[0];
    const float* hist   = (const float*)d_in[1];
    const int*   mask   = (const int*)d_in[2];
    const float* Wq     = (const float*)d_in[3];
    const float* Wk     = (const float*)d_in[4];
    const float* Wv     = (const float*)d_in[5];
    const float* Wo     = (const float*)d_in[6];
    float* outp = (float*)d_out;
    float* MP   = (float*)d_ws;                 // 8192 floats: M, then P

    prep_kernel<<<32, 256, 0, stream>>>(Wq, Wk, Wv, Wo, MP);
    attn_kernel<<<B_TOT / 4, 256, 0, stream>>>(hist, mask, target, MP, outp);
}